// Round 18
// baseline (146.866 us; speedup 1.0000x reference)
//
#include <hip/hip_runtime.h>
#include <math.h>

#define B_  8192
#define F_  256
#define T_  32
#define NI_ 63
#define NL_ 64
#define C_  100
#define K2_ (T_*NL_)       // 2048 = GEMM2 K
#define NG  8              // tree groups (partial buffers)
#define TPG 4              // trees per group

typedef unsigned short u16;
typedef __attribute__((ext_vector_type(8))) short bf16x8;   // MFMA A/B frag
typedef __attribute__((ext_vector_type(4))) float f32x4;    // MFMA C/D frag
typedef __attribute__((ext_vector_type(8))) unsigned short u16x8;

__device__ __forceinline__ u16 f2bf(float f) {
    unsigned int u = __float_as_uint(f);
    u += 0x7fffu + ((u >> 16) & 1u);      // RNE
    return (u16)(u >> 16);
}

// ws layout (bytes):
//   swb  : u16 [T_][NI_][F_]   = 1,032,192
//   lcpT : u16 [112][K2_]      =   458,752
//   part : f32 [NG][B_][112]   = 29,360,128  (store path)
#define WSB_SWB   0
#define WSB_LCPT  (T_*NI_*F_*2)
#define WSB_PART  ((size_t)WSB_LCPT + 112*K2_*2)          //  1,490,944
#define WSB_ATOM  WSB_PART                                 // atomic path total
#define WSB_STORE (WSB_PART + (size_t)NG*B_*112*4)         // 30,851,072

// ---- prep: cvt sw->bf16 + lcp table (+ zero-out section, atomic path only) ----
#define SWBLK  (T_*NI_*F_/256)    // 2016
#define LCPBLK (T_*NL_/256)       // 8
#define ZBLK   (B_*C_/256)        // 3200
__global__ void k_prep(const float* __restrict__ sw, const float* __restrict__ ll,
                       const float* __restrict__ tw, const float* __restrict__ logT,
                       u16* __restrict__ swb, u16* __restrict__ lcpT,
                       float* __restrict__ out) {
    int blk = blockIdx.x, tid = threadIdx.x;
    if (blk < SWBLK) { int i = blk * 256 + tid; swb[i] = f2bf(sw[i]); return; }
    blk -= SWBLK;
    if (blk >= LCPBLK) {                    // zero section (atomic path only)
        out[(blk - LCPBLK) * 256 + tid] = 0.f;
        return;
    }
    int idx = blk * 256 + tid;              // leaf row: t*64 + l
    int t = idx >> 6;
    float temp = __expf(logT[0]);
    temp = fminf(fmaxf(temp, 0.1f), 5.0f);
    float invt = 1.0f / temp;

    float m = -1e30f;
    for (int j = 0; j < T_; ++j) m = fmaxf(m, tw[j]);
    float s = 0.f;
    for (int j = 0; j < T_; ++j) s += __expf(tw[j] - m);
    float wt = __expf(tw[t] - m) / s;

    const float* row = ll + (size_t)idx * C_;
    float m2 = -1e30f;
    for (int c = 0; c < C_; ++c) m2 = fmaxf(m2, row[c]);
    float s2 = 0.f;
    for (int c = 0; c < C_; ++c) s2 += __expf((row[c] - m2) * invt);
    float sc = wt / s2;
    for (int c = 0; c < C_; ++c)
        lcpT[(size_t)c * K2_ + idx] = f2bf(sc * __expf((row[c] - m2) * invt));
    for (int c = C_; c < 112; ++c)
        lcpT[(size_t)c * K2_ + idx] = 0;
}

// ---- fused: pipelined LDS staging; 2 m-tiles/wave (B-frag reads amortized x2)
// grid (B_/128, NG), block 256 (4 waves x 32 rows); TPG trees per block.
__global__ __launch_bounds__(256, 2)
void k_fused(const float* __restrict__ x, const u16* __restrict__ swb,
             const float* __restrict__ sb, const float* __restrict__ logT,
             const u16* __restrict__ lcpT, float* __restrict__ dst, int storeMode) {
    __shared__ u16   swS[63 * 264];       // 63 x 528B (stride 264): 33,264 B
    __shared__ u16   lcpS[8 * 112 * 8];   // [o=l/8][c][8] frag-contiguous: 14,336 B
    __shared__ float slog[4][16][66];     // per-wave sigmoid tile: 16,896 B
    int tid  = threadIdx.x;
    int w    = tid >> 6;
    int lane = tid & 63;
    int col  = lane & 15;
    int quad = lane >> 4;
    int mb0  = blockIdx.x * 128 + w * 32; // wave's 32 batch rows (2 m-tiles)
    int tg   = blockIdx.y;

    float temp = __expf(logT[0]);
    temp = fminf(fmaxf(temp, 0.1f), 5.0f);
    float invt = 1.0f / temp;

    // A-frags for both m-tiles, packed from fp32 x (one-time)
    bf16x8 afr[2][8];
    #pragma unroll
    for (int m = 0; m < 2; ++m) {
        #pragma unroll
        for (int ks = 0; ks < 8; ++ks) {
            const float4* px = (const float4*)(x + (size_t)(mb0 + m * 16 + col) * F_
                                               + ks * 32 + quad * 8);
            float4 v0 = px[0], v1 = px[1];
            bf16x8 a;
            a[0] = (short)f2bf(v0.x); a[1] = (short)f2bf(v0.y);
            a[2] = (short)f2bf(v0.z); a[3] = (short)f2bf(v0.w);
            a[4] = (short)f2bf(v1.x); a[5] = (short)f2bf(v1.y);
            a[6] = (short)f2bf(v1.z); a[7] = (short)f2bf(v1.w);
            afr[m][ks] = a;
        }
    }

    // prefetch tile 0
    u16x8 pf_sw[8];
    u16x8 pf_lcp[4];
    {
        int t0 = tg * TPG;
        const char* gsrc = (const char*)(swb + (size_t)t0 * NI_ * F_);
        #pragma unroll
        for (int r = 0; r < 8; ++r) {
            int g = r * 4096 + tid * 16;
            if (g < NI_ * F_ * 2) pf_sw[r] = *(const u16x8*)(gsrc + g);
        }
        #pragma unroll
        for (int r = 0; r < 4; ++r) {
            int idx = r * 256 + tid;
            if (idx < 896) {
                int o = idx / 112, c = idx - o * 112;
                pf_lcp[r] = *(const u16x8*)(lcpT + (size_t)c * K2_ + t0 * NL_ + o * 8);
            }
        }
    }

    f32x4 accO[2][7];
    #pragma unroll
    for (int m = 0; m < 2; ++m)
        #pragma unroll
        for (int i = 0; i < 7; ++i) accO[m][i] = (f32x4){0.f, 0.f, 0.f, 0.f};

    #pragma unroll 1
    for (int ti = 0; ti < TPG; ++ti) {
        int t = tg * TPG + ti;

        __syncthreads();   // all waves done reading previous tile
        #pragma unroll
        for (int r = 0; r < 8; ++r) {
            int g = r * 4096 + tid * 16;
            if (g < NI_ * F_ * 2) {
                int n   = g >> 9;
                int k16 = (g & 511) >> 4;
                *(u16x8*)&swS[n * 264 + k16 * 8] = pf_sw[r];
            }
        }
        #pragma unroll
        for (int r = 0; r < 4; ++r) {
            int idx = r * 256 + tid;
            if (idx < 896) {
                int o = idx / 112, c = idx - o * 112;
                *(u16x8*)&lcpS[(o * 112 + c) * 8] = pf_lcp[r];
            }
        }
        __syncthreads();   // tile visible

        if (ti + 1 < TPG) {        // prefetch next tile (overlaps compute)
            int tn = t + 1;
            const char* gsrc = (const char*)(swb + (size_t)tn * NI_ * F_);
            #pragma unroll
            for (int r = 0; r < 8; ++r) {
                int g = r * 4096 + tid * 16;
                if (g < NI_ * F_ * 2) pf_sw[r] = *(const u16x8*)(gsrc + g);
            }
            #pragma unroll
            for (int r = 0; r < 4; ++r) {
                int idx = r * 256 + tid;
                if (idx < 896) {
                    int o = idx / 112, c = idx - o * 112;
                    pf_lcp[r] = *(const u16x8*)(lcpT + (size_t)c * K2_ + tn * NL_ + o * 8);
                }
            }
        }

        // ---- GEMM1: logits[32 b][64 n]; each B-frag read feeds 2 MFMAs
        f32x4 acc[2][4];
        #pragma unroll
        for (int m = 0; m < 2; ++m)
            #pragma unroll
            for (int i = 0; i < 4; ++i) acc[m][i] = (f32x4){0.f, 0.f, 0.f, 0.f};
        #pragma unroll
        for (int ks = 0; ks < 8; ++ks) {
            #pragma unroll
            for (int nt = 0; nt < 4; ++nt) {
                int n  = nt * 16 + col;
                int ne = n > 62 ? 62 : n;
                bf16x8 bfr = *(const bf16x8*)&swS[ne * 264 + ks * 32 + quad * 8];
                acc[0][nt] = __builtin_amdgcn_mfma_f32_16x16x32_bf16(afr[0][ks], bfr, acc[0][nt], 0, 0, 0);
                acc[1][nt] = __builtin_amdgcn_mfma_f32_16x16x32_bf16(afr[1][ks], bfr, acc[1][nt], 0, 0, 0);
            }
        }

        // ---- per m-tile: epilogue -> walk -> GEMM2 (slog reused in-wave)
        #pragma unroll
        for (int m = 0; m < 2; ++m) {
            asm volatile("s_waitcnt lgkmcnt(0)" ::: "memory");  // prior slog readers done
            #pragma unroll
            for (int nt = 0; nt < 4; ++nt) {
                int n = nt * 16 + col;
                float bias = (n < NI_) ? sb[t * NI_ + n] : 0.f;
                #pragma unroll
                for (int r = 0; r < 4; ++r) {
                    float lg = (acc[m][nt][r] + bias) * invt;
                    slog[w][quad * 4 + r][n] = 1.0f / (1.0f + __expf(-lg));
                }
            }
            asm volatile("s_waitcnt lgkmcnt(0)" ::: "memory");  // writes visible in-wave

            bf16x8 af0, af1;
            #pragma unroll
            for (int grp = 0; grp < 2; ++grp) {
                int s = (grp ? 11 : 7) + quad;
                float pref = 1.0f;
                int node = s;
                #pragma unroll
                for (int d = 0; d < 3; ++d) {
                    int par = (node - 1) >> 1;
                    float g = slog[w][col][par];
                    pref = (node & 1) ? (pref - pref * g) : (pref * g);  // odd=left -> 1-g
                    node = par;
                }
                float gs  = slog[w][col][s];
                float gl  = slog[w][col][2 * s + 1];
                float gr  = slog[w][col][2 * s + 2];
                float g00 = slog[w][col][4 * s + 3];
                float g01 = slog[w][col][4 * s + 4];
                float g10 = slog[w][col][4 * s + 5];
                float g11 = slog[w][col][4 * s + 6];
                #pragma unroll
                for (int j = 0; j < 8; ++j) {
                    const int b2 = (j >> 2) & 1, b1 = (j >> 1) & 1, b0 = j & 1;
                    float f3 = b2 ? gs : 1.0f - gs;
                    float c1 = b2 ? gr : gl;
                    float f4 = b1 ? c1 : 1.0f - c1;
                    float c2 = b2 ? (b1 ? g11 : g10) : (b1 ? g01 : g00);
                    float f5 = b0 ? c2 : 1.0f - c2;
                    float p  = pref * f3 * f4 * f5;
                    if (grp == 0) af0[j] = (short)f2bf(p);
                    else          af1[j] = (short)f2bf(p);
                }
            }

            #pragma unroll
            for (int nt = 0; nt < 7; ++nt) {
                int n = nt * 16 + col;
                bf16x8 lb0 = *(const bf16x8*)&lcpS[(quad * 112 + n) * 8];
                bf16x8 lb1 = *(const bf16x8*)&lcpS[((4 + quad) * 112 + n) * 8];
                accO[m][nt] = __builtin_amdgcn_mfma_f32_16x16x32_bf16(af0, lb0, accO[m][nt], 0, 0, 0);
                accO[m][nt] = __builtin_amdgcn_mfma_f32_16x16x32_bf16(af1, lb1, accO[m][nt], 0, 0, 0);
            }
        }
    }

    if (storeMode) {
        float* pp = dst + (size_t)tg * B_ * 112;
        #pragma unroll
        for (int m = 0; m < 2; ++m) {
            #pragma unroll
            for (int nt = 0; nt < 7; ++nt) {
                int c = nt * 16 + col;
                #pragma unroll
                for (int r = 0; r < 4; ++r) {
                    int b = mb0 + m * 16 + quad * 4 + r;
                    pp[(size_t)b * 112 + c] = accO[m][nt][r];
                }
            }
        }
    } else {
        #pragma unroll
        for (int m = 0; m < 2; ++m) {
            #pragma unroll
            for (int nt = 0; nt < 7; ++nt) {
                int c = nt * 16 + col;
                if (c < C_) {
                    #pragma unroll
                    for (int r = 0; r < 4; ++r) {
                        int b = mb0 + m * 16 + quad * 4 + r;
                        atomicAdd(&dst[(size_t)b * C_ + c], accO[m][nt][r]);
                    }
                }
            }
        }
    }
}

// ---- reduce: out[b][c] = sum_tg part[tg][b][c] ----
__global__ void k_red(const float* __restrict__ part, float* __restrict__ out) {
    int idx = blockIdx.x * 256 + threadIdx.x;    // over B_*112
    int b = idx / 112, c = idx - b * 112;
    if (c < C_) {
        float s = 0.f;
        #pragma unroll
        for (int tg = 0; tg < NG; ++tg)
            s += part[((size_t)tg * B_ + b) * 112 + c];
        out[(size_t)b * C_ + c] = s;
    }
}

// ---- guard path: zero fp32 output ----
__global__ void k_zf(float* __restrict__ out, int n) {
    int i = blockIdx.x * 256 + threadIdx.x;
    if (i < n) out[i] = 0.f;
}

// ---- zero-ws fallback (R5-verified structure, fp32 I/O) ----
__global__ void k_mono(const float* __restrict__ x, const float* __restrict__ sw,
                       const float* __restrict__ sb, const float* __restrict__ ll,
                       const float* __restrict__ tw, const float* __restrict__ logT,
                       float* __restrict__ outg) {
    __shared__ float slcp[NL_ * C_];
    int tid = threadIdx.x;
    int b = blockIdx.x * 256 + tid;

    float temp = __expf(logT[0]);
    temp = fminf(fmaxf(temp, 0.1f), 5.0f);
    float invt = 1.0f / temp;

    float m = -1e30f;
    for (int j = 0; j < T_; ++j) m = fmaxf(m, tw[j]);
    float sden = 0.f;
    for (int j = 0; j < T_; ++j) sden += __expf(tw[j] - m);

    float acc[C_];
    #pragma unroll
    for (int c = 0; c < C_; ++c) acc[c] = 0.f;

    for (int t = 0; t < T_; ++t) {
        __syncthreads();
        {
            int l = tid & 63, cq = tid >> 6;
            float wt = __expf(tw[t] - m) / sden;
            const float* row = ll + ((size_t)t * NL_ + l) * C_;
            float m2 = -1e30f;
            for (int c = 0; c < C_; ++c) m2 = fmaxf(m2, row[c]);
            float s2 = 0.f;
            for (int c = 0; c < C_; ++c) s2 += __expf((row[c] - m2) * invt);
            float sc = wt / s2;
            for (int c = cq * 25; c < cq * 25 + 25; ++c)
                slcp[l * C_ + c] = sc * __expf((row[c] - m2) * invt);
        }
        __syncthreads();

        float an[NI_];
        #pragma unroll
        for (int n = 0; n < NI_; ++n) an[n] = 0.f;
        for (int k = 0; k < F_; ++k) {
            float xv = x[(size_t)b * F_ + k];
            #pragma unroll
            for (int n = 0; n < NI_; ++n)
                an[n] = fmaf(xv, sw[((size_t)t * NI_ + n) * F_ + k], an[n]);
        }
        #pragma unroll
        for (int n = 0; n < NI_; ++n) {
            float lg = (an[n] + sb[t * NI_ + n]) * invt;
            an[n] = 1.0f / (1.0f + __expf(-lg));
        }
        #pragma unroll
        for (int l = 0; l < NL_; ++l) {
            int node = l + NI_;
            float p = 1.0f;
            #pragma unroll
            for (int d = 0; d < 6; ++d) {
                int par = (node - 1) >> 1;
                float gv = an[par];
                p = (node & 1) ? (p - p * gv) : (p * gv);
                node = par;
            }
            #pragma unroll
            for (int c = 0; c < C_; ++c)
                acc[c] = fmaf(p, slcp[l * C_ + c], acc[c]);
        }
    }
    for (int c = 0; c < C_; ++c)
        outg[(size_t)b * C_ + c] = acc[c];
}

extern "C" void kernel_launch(void* const* d_in, const int* in_sizes, int n_in,
                              void* d_out, int out_size, void* d_ws, size_t ws_size,
                              hipStream_t stream) {
    bool ok = (n_in >= 6)
           && (in_sizes[0] == B_ * F_)
           && (in_sizes[1] == T_ * NI_ * F_)
           && (in_sizes[2] == T_ * NI_)
           && (in_sizes[3] == T_ * NL_ * C_)
           && (in_sizes[4] == T_)
           && (in_sizes[5] == 1)
           && (out_size == B_ * C_);
    if (!ok) {
        k_zf<<<(out_size + 255) / 256, 256, 0, stream>>>((float*)d_out, out_size);
        return;
    }

    const float* x    = (const float*)d_in[0];
    const float* sw   = (const float*)d_in[1];
    const float* sb   = (const float*)d_in[2];
    const float* ll   = (const float*)d_in[3];
    const float* tw   = (const float*)d_in[4];
    const float* logT = (const float*)d_in[5];
    float* out = (float*)d_out;

    if (ws_size >= WSB_STORE) {
        u16*   swb  = (u16*)((char*)d_ws + WSB_SWB);
        u16*   lcpT = (u16*)((char*)d_ws + WSB_LCPT);
        float* part = (float*)((char*)d_ws + WSB_PART);

        k_prep <<<SWBLK + LCPBLK, 256, 0, stream>>>(sw, ll, tw, logT, swb, lcpT, out);
        k_fused<<<dim3(B_ / 128, NG), 256, 0, stream>>>(x, swb, sb, logT, lcpT, part, 1);
        k_red  <<<(B_ * 112) / 256, 256, 0, stream>>>(part, out);
    } else if (ws_size >= WSB_ATOM) {
        u16* swb  = (u16*)((char*)d_ws + WSB_SWB);
        u16* lcpT = (u16*)((char*)d_ws + WSB_LCPT);

        k_prep <<<SWBLK + LCPBLK + ZBLK, 256, 0, stream>>>(sw, ll, tw, logT, swb, lcpT, out);
        k_fused<<<dim3(B_ / 128, NG), 256, 0, stream>>>(x, swb, sb, logT, lcpT, out, 0);
    } else {
        k_mono<<<B_ / 256, 256, 0, stream>>>(x, sw, sb, ll, tw, logT, out);
    }
}

// Round 19
// 129.454 us; speedup vs baseline: 1.1345x; 1.1345x over previous
//
#include <hip/hip_runtime.h>
#include <math.h>

#define B_  8192
#define F_  256
#define T_  32
#define NI_ 63
#define NL_ 64
#define C_  100
#define K2_ (T_*NL_)       // 2048 = GEMM2 K
#define NG  4              // tree groups (partials fit per-XCD L2: 0.9 MB/XCD bf16)
#define TPG 8              // trees per group

typedef unsigned short u16;
typedef __attribute__((ext_vector_type(8))) short bf16x8;   // MFMA A/B frag
typedef __attribute__((ext_vector_type(4))) float f32x4;    // MFMA C/D frag
typedef __attribute__((ext_vector_type(8))) unsigned short u16x8;

__device__ __forceinline__ u16 f2bf(float f) {
    unsigned int u = __float_as_uint(f);
    u += 0x7fffu + ((u >> 16) & 1u);      // RNE
    return (u16)(u >> 16);
}
__device__ __forceinline__ float bf2f(u16 u) {
    return __uint_as_float(((unsigned int)u) << 16);
}

// ws layout (bytes):
//   swb  : u16 [T_][NI_][F_]   = 1,032,192
//   lcpT : u16 [112][K2_]      =   458,752
//   part : u16 [NG][B_][112]   = 7,340,032   (bf16 partials, store path)
#define WSB_SWB   0
#define WSB_LCPT  (T_*NI_*F_*2)
#define WSB_PART  ((size_t)WSB_LCPT + 112*K2_*2)          //  1,490,944
#define WSB_ATOM  WSB_PART                                 // atomic path total
#define WSB_STORE (WSB_PART + (size_t)NG*B_*112*2)         //  8,830,976

// ---- prep: cvt sw->bf16 + lcp table (+ zero-out section, atomic path only) ----
#define SWBLK  (T_*NI_*F_/256)    // 2016
#define LCPBLK (T_*NL_/256)       // 8
#define ZBLK   (B_*C_/256)        // 3200
__global__ void k_prep(const float* __restrict__ sw, const float* __restrict__ ll,
                       const float* __restrict__ tw, const float* __restrict__ logT,
                       u16* __restrict__ swb, u16* __restrict__ lcpT,
                       float* __restrict__ out) {
    int blk = blockIdx.x, tid = threadIdx.x;
    if (blk < SWBLK) { int i = blk * 256 + tid; swb[i] = f2bf(sw[i]); return; }
    blk -= SWBLK;
    if (blk >= LCPBLK) {                    // zero section (atomic path only)
        out[(blk - LCPBLK) * 256 + tid] = 0.f;
        return;
    }
    int idx = blk * 256 + tid;              // leaf row: t*64 + l
    int t = idx >> 6;
    float temp = __expf(logT[0]);
    temp = fminf(fmaxf(temp, 0.1f), 5.0f);
    float invt = 1.0f / temp;

    float m = -1e30f;
    for (int j = 0; j < T_; ++j) m = fmaxf(m, tw[j]);
    float s = 0.f;
    for (int j = 0; j < T_; ++j) s += __expf(tw[j] - m);
    float wt = __expf(tw[t] - m) / s;

    const float* row = ll + (size_t)idx * C_;
    float m2 = -1e30f;
    for (int c = 0; c < C_; ++c) m2 = fmaxf(m2, row[c]);
    float s2 = 0.f;
    for (int c = 0; c < C_; ++c) s2 += __expf((row[c] - m2) * invt);
    float sc = wt / s2;
    for (int c = 0; c < C_; ++c)
        lcpT[(size_t)c * K2_ + idx] = f2bf(sc * __expf((row[c] - m2) * invt));
    for (int c = C_; c < 112; ++c)
        lcpT[(size_t)c * K2_ + idx] = 0;
}

// ---- fused (R17-proven pipeline, 16 rows/wave): bf16 partial stores (mode 1)
//      or fp32 atomicAdd into out (mode 0, R16-proven fallback)
__global__ __launch_bounds__(256, 2)
void k_fused(const float* __restrict__ x, const u16* __restrict__ swb,
             const float* __restrict__ sb, const float* __restrict__ logT,
             const u16* __restrict__ lcpT, void* __restrict__ dst, int storeMode) {
    __shared__ u16   swS[63 * 264];       // 63 x 528B (stride 264): 33,264 B
    __shared__ u16   lcpS[8 * 112 * 8];   // [o=l/8][c][8] frag-contiguous: 14,336 B
    __shared__ float slog[4][16][66];     // per-wave sigmoid tile: 16,896 B
    int tid  = threadIdx.x;
    int w    = tid >> 6;
    int lane = tid & 63;
    int col  = lane & 15;
    int quad = lane >> 4;
    int mb   = blockIdx.x * 64 + w * 16;
    int tg   = blockIdx.y;

    float temp = __expf(logT[0]);
    temp = fminf(fmaxf(temp, 0.1f), 5.0f);
    float invt = 1.0f / temp;

    bf16x8 afr[8];
    #pragma unroll
    for (int ks = 0; ks < 8; ++ks) {
        const float4* px = (const float4*)(x + (size_t)(mb + col) * F_ + ks * 32 + quad * 8);
        float4 v0 = px[0], v1 = px[1];
        bf16x8 a;
        a[0] = (short)f2bf(v0.x); a[1] = (short)f2bf(v0.y);
        a[2] = (short)f2bf(v0.z); a[3] = (short)f2bf(v0.w);
        a[4] = (short)f2bf(v1.x); a[5] = (short)f2bf(v1.y);
        a[6] = (short)f2bf(v1.z); a[7] = (short)f2bf(v1.w);
        afr[ks] = a;
    }

    // prefetch tile 0
    u16x8 pf_sw[8];
    u16x8 pf_lcp[4];
    {
        int t0 = tg * TPG;
        const char* gsrc = (const char*)(swb + (size_t)t0 * NI_ * F_);
        #pragma unroll
        for (int r = 0; r < 8; ++r) {
            int g = r * 4096 + tid * 16;
            if (g < NI_ * F_ * 2) pf_sw[r] = *(const u16x8*)(gsrc + g);
        }
        #pragma unroll
        for (int r = 0; r < 4; ++r) {
            int idx = r * 256 + tid;
            if (idx < 896) {
                int o = idx / 112, c = idx - o * 112;
                pf_lcp[r] = *(const u16x8*)(lcpT + (size_t)c * K2_ + t0 * NL_ + o * 8);
            }
        }
    }

    f32x4 accO[7];
    #pragma unroll
    for (int i = 0; i < 7; ++i) accO[i] = (f32x4){0.f, 0.f, 0.f, 0.f};

    #pragma unroll 1
    for (int ti = 0; ti < TPG; ++ti) {
        int t = tg * TPG + ti;

        __syncthreads();   // all waves done reading previous tile
        #pragma unroll
        for (int r = 0; r < 8; ++r) {
            int g = r * 4096 + tid * 16;
            if (g < NI_ * F_ * 2) {
                int n   = g >> 9;
                int k16 = (g & 511) >> 4;
                *(u16x8*)&swS[n * 264 + k16 * 8] = pf_sw[r];
            }
        }
        #pragma unroll
        for (int r = 0; r < 4; ++r) {
            int idx = r * 256 + tid;
            if (idx < 896) {
                int o = idx / 112, c = idx - o * 112;
                *(u16x8*)&lcpS[(o * 112 + c) * 8] = pf_lcp[r];
            }
        }
        __syncthreads();   // tile visible

        if (ti + 1 < TPG) {        // prefetch next tile (overlaps compute)
            int tn = t + 1;
            const char* gsrc = (const char*)(swb + (size_t)tn * NI_ * F_);
            #pragma unroll
            for (int r = 0; r < 8; ++r) {
                int g = r * 4096 + tid * 16;
                if (g < NI_ * F_ * 2) pf_sw[r] = *(const u16x8*)(gsrc + g);
            }
            #pragma unroll
            for (int r = 0; r < 4; ++r) {
                int idx = r * 256 + tid;
                if (idx < 896) {
                    int o = idx / 112, c = idx - o * 112;
                    pf_lcp[r] = *(const u16x8*)(lcpT + (size_t)c * K2_ + tn * NL_ + o * 8);
                }
            }
        }

        // ---- GEMM1
        f32x4 acc[4];
        #pragma unroll
        for (int i = 0; i < 4; ++i) acc[i] = (f32x4){0.f, 0.f, 0.f, 0.f};
        #pragma unroll
        for (int ks = 0; ks < 8; ++ks) {
            #pragma unroll
            for (int nt = 0; nt < 4; ++nt) {
                int n  = nt * 16 + col;
                int ne = n > 62 ? 62 : n;
                bf16x8 bfr = *(const bf16x8*)&swS[ne * 264 + ks * 32 + quad * 8];
                acc[nt] = __builtin_amdgcn_mfma_f32_16x16x32_bf16(afr[ks], bfr, acc[nt], 0, 0, 0);
            }
        }

        // ---- epilogue: bias+sigmoid -> slog
        asm volatile("s_waitcnt lgkmcnt(0)" ::: "memory");
        #pragma unroll
        for (int nt = 0; nt < 4; ++nt) {
            int n = nt * 16 + col;
            float bias = (n < NI_) ? sb[t * NI_ + n] : 0.f;
            #pragma unroll
            for (int r = 0; r < 4; ++r) {
                float lg = (acc[nt][r] + bias) * invt;
                slog[w][quad * 4 + r][n] = 1.0f / (1.0f + __expf(-lg));
            }
        }
        asm volatile("s_waitcnt lgkmcnt(0)" ::: "memory");

        // ---- leaf walk
        bf16x8 af0, af1;
        #pragma unroll
        for (int grp = 0; grp < 2; ++grp) {
            int s = (grp ? 11 : 7) + quad;
            float pref = 1.0f;
            int node = s;
            #pragma unroll
            for (int d = 0; d < 3; ++d) {
                int par = (node - 1) >> 1;
                float g = slog[w][col][par];
                pref = (node & 1) ? (pref - pref * g) : (pref * g);  // odd=left -> 1-g
                node = par;
            }
            float gs  = slog[w][col][s];
            float gl  = slog[w][col][2 * s + 1];
            float gr  = slog[w][col][2 * s + 2];
            float g00 = slog[w][col][4 * s + 3];
            float g01 = slog[w][col][4 * s + 4];
            float g10 = slog[w][col][4 * s + 5];
            float g11 = slog[w][col][4 * s + 6];
            #pragma unroll
            for (int j = 0; j < 8; ++j) {
                const int b2 = (j >> 2) & 1, b1 = (j >> 1) & 1, b0 = j & 1;
                float f3 = b2 ? gs : 1.0f - gs;
                float c1 = b2 ? gr : gl;
                float f4 = b1 ? c1 : 1.0f - c1;
                float c2 = b2 ? (b1 ? g11 : g10) : (b1 ? g01 : g00);
                float f5 = b0 ? c2 : 1.0f - c2;
                float p  = pref * f3 * f4 * f5;
                if (grp == 0) af0[j] = (short)f2bf(p);
                else          af1[j] = (short)f2bf(p);
            }
        }

        // ---- GEMM2
        #pragma unroll
        for (int nt = 0; nt < 7; ++nt) {
            int n = nt * 16 + col;
            bf16x8 lb0 = *(const bf16x8*)&lcpS[(quad * 112 + n) * 8];
            bf16x8 lb1 = *(const bf16x8*)&lcpS[((4 + quad) * 112 + n) * 8];
            accO[nt] = __builtin_amdgcn_mfma_f32_16x16x32_bf16(af0, lb0, accO[nt], 0, 0, 0);
            accO[nt] = __builtin_amdgcn_mfma_f32_16x16x32_bf16(af1, lb1, accO[nt], 0, 0, 0);
        }
    }

    if (storeMode) {
        // bf16 partial stores to part[tg][b][112] — no RMW, half the bytes
        u16* pp = (u16*)dst + (size_t)tg * B_ * 112;
        #pragma unroll
        for (int nt = 0; nt < 7; ++nt) {
            int c = nt * 16 + col;
            #pragma unroll
            for (int r = 0; r < 4; ++r) {
                int b = mb + quad * 4 + r;
                pp[(size_t)b * 112 + c] = f2bf(accO[nt][r]);
            }
        }
    } else {
        // R16-proven atomic path
        float* od = (float*)dst;
        #pragma unroll
        for (int nt = 0; nt < 7; ++nt) {
            int c = nt * 16 + col;
            if (c < C_) {
                #pragma unroll
                for (int r = 0; r < 4; ++r) {
                    int b = mb + quad * 4 + r;
                    atomicAdd(&od[(size_t)b * C_ + c], accO[nt][r]);
                }
            }
        }
    }
}

// ---- reduce: out[b][c] = sum_tg bf2f(part[tg][b][c]) ----
__global__ void k_red(const u16* __restrict__ part, float* __restrict__ out) {
    int idx = blockIdx.x * 256 + threadIdx.x;    // over B_*112
    int b = idx / 112, c = idx - b * 112;
    if (c < C_) {
        float s = 0.f;
        #pragma unroll
        for (int tg = 0; tg < NG; ++tg)
            s += bf2f(part[((size_t)tg * B_ + b) * 112 + c]);
        out[(size_t)b * C_ + c] = s;
    }
}

// ---- guard path: zero fp32 output ----
__global__ void k_zf(float* __restrict__ out, int n) {
    int i = blockIdx.x * 256 + threadIdx.x;
    if (i < n) out[i] = 0.f;
}

// ---- zero-ws fallback (R5-verified structure, fp32 I/O) ----
__global__ void k_mono(const float* __restrict__ x, const float* __restrict__ sw,
                       const float* __restrict__ sb, const float* __restrict__ ll,
                       const float* __restrict__ tw, const float* __restrict__ logT,
                       float* __restrict__ outg) {
    __shared__ float slcp[NL_ * C_];
    int tid = threadIdx.x;
    int b = blockIdx.x * 256 + tid;

    float temp = __expf(logT[0]);
    temp = fminf(fmaxf(temp, 0.1f), 5.0f);
    float invt = 1.0f / temp;

    float m = -1e30f;
    for (int j = 0; j < T_; ++j) m = fmaxf(m, tw[j]);
    float sden = 0.f;
    for (int j = 0; j < T_; ++j) sden += __expf(tw[j] - m);

    float acc[C_];
    #pragma unroll
    for (int c = 0; c < C_; ++c) acc[c] = 0.f;

    for (int t = 0; t < T_; ++t) {
        __syncthreads();
        {
            int l = tid & 63, cq = tid >> 6;
            float wt = __expf(tw[t] - m) / sden;
            const float* row = ll + ((size_t)t * NL_ + l) * C_;
            float m2 = -1e30f;
            for (int c = 0; c < C_; ++c) m2 = fmaxf(m2, row[c]);
            float s2 = 0.f;
            for (int c = 0; c < C_; ++c) s2 += __expf((row[c] - m2) * invt);
            float sc = wt / s2;
            for (int c = cq * 25; c < cq * 25 + 25; ++c)
                slcp[l * C_ + c] = sc * __expf((row[c] - m2) * invt);
        }
        __syncthreads();

        float an[NI_];
        #pragma unroll
        for (int n = 0; n < NI_; ++n) an[n] = 0.f;
        for (int k = 0; k < F_; ++k) {
            float xv = x[(size_t)b * F_ + k];
            #pragma unroll
            for (int n = 0; n < NI_; ++n)
                an[n] = fmaf(xv, sw[((size_t)t * NI_ + n) * F_ + k], an[n]);
        }
        #pragma unroll
        for (int n = 0; n < NI_; ++n) {
            float lg = (an[n] + sb[t * NI_ + n]) * invt;
            an[n] = 1.0f / (1.0f + __expf(-lg));
        }
        #pragma unroll
        for (int l = 0; l < NL_; ++l) {
            int node = l + NI_;
            float p = 1.0f;
            #pragma unroll
            for (int d = 0; d < 6; ++d) {
                int par = (node - 1) >> 1;
                float gv = an[par];
                p = (node & 1) ? (p - p * gv) : (p * gv);
                node = par;
            }
            #pragma unroll
            for (int c = 0; c < C_; ++c)
                acc[c] = fmaf(p, slcp[l * C_ + c], acc[c]);
        }
    }
    for (int c = 0; c < C_; ++c)
        outg[(size_t)b * C_ + c] = acc[c];
}

extern "C" void kernel_launch(void* const* d_in, const int* in_sizes, int n_in,
                              void* d_out, int out_size, void* d_ws, size_t ws_size,
                              hipStream_t stream) {
    bool ok = (n_in >= 6)
           && (in_sizes[0] == B_ * F_)
           && (in_sizes[1] == T_ * NI_ * F_)
           && (in_sizes[2] == T_ * NI_)
           && (in_sizes[3] == T_ * NL_ * C_)
           && (in_sizes[4] == T_)
           && (in_sizes[5] == 1)
           && (out_size == B_ * C_);
    if (!ok) {
        k_zf<<<(out_size + 255) / 256, 256, 0, stream>>>((float*)d_out, out_size);
        return;
    }

    const float* x    = (const float*)d_in[0];
    const float* sw   = (const float*)d_in[1];
    const float* sb   = (const float*)d_in[2];
    const float* ll   = (const float*)d_in[3];
    const float* tw   = (const float*)d_in[4];
    const float* logT = (const float*)d_in[5];
    float* out = (float*)d_out;

    if (ws_size >= WSB_STORE) {
        u16* swb  = (u16*)((char*)d_ws + WSB_SWB);
        u16* lcpT = (u16*)((char*)d_ws + WSB_LCPT);
        u16* part = (u16*)((char*)d_ws + WSB_PART);

        k_prep <<<SWBLK + LCPBLK, 256, 0, stream>>>(sw, ll, tw, logT, swb, lcpT, out);
        k_fused<<<dim3(B_ / 64, NG), 256, 0, stream>>>(x, swb, sb, logT, lcpT, part, 1);
        k_red  <<<(B_ * 112) / 256, 256, 0, stream>>>(part, out);
    } else if (ws_size >= WSB_ATOM) {
        u16* swb  = (u16*)((char*)d_ws + WSB_SWB);
        u16* lcpT = (u16*)((char*)d_ws + WSB_LCPT);

        k_prep <<<SWBLK + LCPBLK + ZBLK, 256, 0, stream>>>(sw, ll, tw, logT, swb, lcpT, out);
        k_fused<<<dim3(B_ / 64, NG), 256, 0, stream>>>(x, swb, sb, logT, lcpT, d_out, 0);
    } else {
        k_mono<<<B_ / 256, 256, 0, stream>>>(x, sw, sb, ll, tw, logT, out);
    }
}